// Round 5
// baseline (891.037 us; speedup 1.0000x reference)
//
#include <hip/hip_runtime.h>

// Problem constants (B,S,D,H fixed by reference)
constexpr int Bn = 32, Sn = 512, Dn = 512, Hn = 8, DKn = 64;

typedef __attribute__((ext_vector_type(8))) short bf16x8;
typedef __attribute__((ext_vector_type(8))) _Float16 f16x8;
typedef __attribute__((ext_vector_type(4))) _Float16 f16x4;
typedef __attribute__((ext_vector_type(4))) float f32x4;

#define DEV_INLINE __device__ __forceinline__

DEV_INLINE float bf2f(unsigned int u) { return __uint_as_float(u << 16); }

DEV_INLINE unsigned short f2bf(float f) {
  unsigned int u = __float_as_uint(f);
  u += 0x7fffu + ((u >> 16) & 1u);   // round-to-nearest-even; inputs finite
  return (unsigned short)(u >> 16);
}

DEV_INLINE void unpack8(const uint4 r, float* o) {
  o[0] = bf2f(r.x & 0xffffu); o[1] = bf2f(r.x >> 16);
  o[2] = bf2f(r.y & 0xffffu); o[3] = bf2f(r.y >> 16);
  o[4] = bf2f(r.z & 0xffffu); o[5] = bf2f(r.z >> 16);
  o[6] = bf2f(r.w & 0xffffu); o[7] = bf2f(r.w >> 16);
}

struct F16Pair { _Float16 hi, lo; };
DEV_INLINE F16Pair splitf(float x) {
  F16Pair p;
  p.hi = (_Float16)x;
  p.lo = (_Float16)(x - (float)p.hi);
  return p;
}

// ---------------------------------------------------------------------------
// Fused q+k projection: fp32-accurate GEMM via f16x2 split MFMA.
// blockIdx.z selects {A,W,bias,out,mode}: z=0 -> q, fp32 heads [b,h,s,dk];
// z=1 -> k, f16 hi/lo heads (row = (b*8+h)*512+s, 128 f16: [64 hi | 64 lo]).
// W pre-scaled by 64 at staging (keeps lo normal); epilogue rescales by 1/64.
// ---------------------------------------------------------------------------
__global__ __launch_bounds__(256) void gemm_qk_kernel(
    const float* __restrict__ Aq, const float* __restrict__ Wq,
    const float* __restrict__ bq, float* __restrict__ outq,
    const float* __restrict__ Ak, const float* __restrict__ Wk,
    const float* __restrict__ bk, _Float16* __restrict__ outk) {
  __shared__ _Float16 Ash[128][48], Asl[128][48];
  __shared__ _Float16 Bsh[128][48], Bsl[128][48];  // [n][k] transposed

  const int mode = blockIdx.z;
  const float* A = mode ? Ak : Aq;
  const float* W = mode ? Wk : Wq;
  const float* bias = mode ? bk : bq;

  const int m0 = blockIdx.x * 128, n0 = blockIdx.y * 128;
  const int tid  = threadIdx.x;
  const int lane = tid & 63, wave = tid >> 6;
  const int waveM = wave >> 1, waveN = wave & 1;
  const int col = lane & 15, quad = lane >> 4;

  f32x4 acc[4][4];
#pragma unroll
  for (int mi = 0; mi < 4; ++mi)
#pragma unroll
    for (int ni = 0; ni < 4; ++ni) acc[mi][ni] = (f32x4){0.f, 0.f, 0.f, 0.f};

  for (int k0 = 0; k0 < 512; k0 += 32) {
    __syncthreads();
#pragma unroll
    for (int it = 0; it < 4; ++it) {
      int chunk = tid + it * 256;            // 1024 float4 chunks (128x32)
      int r = chunk >> 3, c4 = chunk & 7;
      float4 v = *(const float4*)(A + (long)(m0 + r) * 512 + k0 + c4 * 4);
      F16Pair p0 = splitf(v.x), p1 = splitf(v.y),
              p2 = splitf(v.z), p3 = splitf(v.w);
      f16x4 hv = {p0.hi, p1.hi, p2.hi, p3.hi};
      f16x4 lv = {p0.lo, p1.lo, p2.lo, p3.lo};
      *(f16x4*)&Ash[r][c4 * 4] = hv;
      *(f16x4*)&Asl[r][c4 * 4] = lv;
    }
#pragma unroll
    for (int it = 0; it < 4; ++it) {
      int chunk = tid + it * 256;            // 32 k-rows x 32 n-chunks
      int r = chunk >> 5, c4 = chunk & 31;
      float4 v = *(const float4*)(W + (long)(k0 + r) * 512 + n0 + c4 * 4);
      F16Pair p0 = splitf(v.x * 64.f), p1 = splitf(v.y * 64.f),
              p2 = splitf(v.z * 64.f), p3 = splitf(v.w * 64.f);
      Bsh[c4 * 4 + 0][r] = p0.hi; Bsl[c4 * 4 + 0][r] = p0.lo;
      Bsh[c4 * 4 + 1][r] = p1.hi; Bsl[c4 * 4 + 1][r] = p1.lo;
      Bsh[c4 * 4 + 2][r] = p2.hi; Bsl[c4 * 4 + 2][r] = p2.lo;
      Bsh[c4 * 4 + 3][r] = p3.hi; Bsl[c4 * 4 + 3][r] = p3.lo;
    }
    __syncthreads();

    f16x8 ah[4], al[4], bh[4], bl[4];
#pragma unroll
    for (int mi = 0; mi < 4; ++mi) {
      ah[mi] = *(const f16x8*)&Ash[waveM * 64 + mi * 16 + col][quad * 8];
      al[mi] = *(const f16x8*)&Asl[waveM * 64 + mi * 16 + col][quad * 8];
    }
#pragma unroll
    for (int ni = 0; ni < 4; ++ni) {
      bh[ni] = *(const f16x8*)&Bsh[waveN * 64 + ni * 16 + col][quad * 8];
      bl[ni] = *(const f16x8*)&Bsl[waveN * 64 + ni * 16 + col][quad * 8];
    }
#pragma unroll
    for (int mi = 0; mi < 4; ++mi)
#pragma unroll
      for (int ni = 0; ni < 4; ++ni) {
        acc[mi][ni] = __builtin_amdgcn_mfma_f32_16x16x32_f16(
            ah[mi], bl[ni], acc[mi][ni], 0, 0, 0);
        acc[mi][ni] = __builtin_amdgcn_mfma_f32_16x16x32_f16(
            al[mi], bh[ni], acc[mi][ni], 0, 0, 0);
        acc[mi][ni] = __builtin_amdgcn_mfma_f32_16x16x32_f16(
            ah[mi], bh[ni], acc[mi][ni], 0, 0, 0);
      }
  }

  // C/D layout: col=lane&15, row=quad*4+reg (m89/m91-verified)
#pragma unroll
  for (int ni = 0; ni < 4; ++ni) {
    const int gn = n0 + waveN * 64 + ni * 16 + col;
    const float bv = bias[gn];
    const int h_ = gn >> 6, dk_ = gn & 63;
#pragma unroll
    for (int mi = 0; mi < 4; ++mi) {
#pragma unroll
      for (int r = 0; r < 4; ++r) {
        const int gm = m0 + waveM * 64 + mi * 16 + quad * 4 + r;
        const int b_ = gm >> 9, s_ = gm & 511;
        const long row = (long)(b_ * 8 + h_) * 512 + s_;
        const float val = acc[mi][ni][r] * 0.015625f + bv;
        if (mode == 0) {
          outq[row * 64 + dk_] = val;
        } else {
          F16Pair p = splitf(val);
          outk[row * 128 + dk_]      = p.hi;
          outk[row * 128 + 64 + dk_] = p.lo;
        }
      }
    }
  }
}

// ---------------------------------------------------------------------------
// bf16 MFMA GEMM (for v-projection and out-projection; continuous-error path)
// ---------------------------------------------------------------------------
template <bool A_IS_BF16, bool HEADS_OUT>
__global__ __launch_bounds__(256) void gemm_kernel(
    const void* __restrict__ Av, const float* __restrict__ W,
    const float* __restrict__ bias, void* __restrict__ outv) {
  __shared__ unsigned short As[128][48];
  __shared__ unsigned short Bs[128][48];  // [n][k]

  const int m0 = blockIdx.x * 128, n0 = blockIdx.y * 128;
  const int tid  = threadIdx.x;
  const int lane = tid & 63, wave = tid >> 6;
  const int waveM = wave >> 1, waveN = wave & 1;
  const int col = lane & 15, quad = lane >> 4;

  f32x4 acc[4][4];
#pragma unroll
  for (int mi = 0; mi < 4; ++mi)
#pragma unroll
    for (int ni = 0; ni < 4; ++ni) acc[mi][ni] = (f32x4){0.f, 0.f, 0.f, 0.f};

  for (int k0 = 0; k0 < 512; k0 += 32) {
    __syncthreads();
    if constexpr (!A_IS_BF16) {
      const float* A = (const float*)Av;
#pragma unroll
      for (int it = 0; it < 4; ++it) {
        int chunk = tid + it * 256;
        int r = chunk >> 3, c4 = chunk & 7;
        float4 v = *(const float4*)(A + (long)(m0 + r) * 512 + k0 + c4 * 4);
        ushort4 w;
        w.x = f2bf(v.x); w.y = f2bf(v.y); w.z = f2bf(v.z); w.w = f2bf(v.w);
        *(ushort4*)&As[r][c4 * 4] = w;
      }
    } else {
      const unsigned short* A = (const unsigned short*)Av;
#pragma unroll
      for (int it = 0; it < 2; ++it) {
        int chunk = tid + it * 256;
        int r = chunk >> 2, c8 = chunk & 3;
        uint4 v = *(const uint4*)(A + (long)(m0 + r) * 512 + k0 + c8 * 8);
        *(uint4*)&As[r][c8 * 8] = v;
      }
    }
#pragma unroll
    for (int it = 0; it < 4; ++it) {
      int chunk = tid + it * 256;
      int r = chunk >> 5, c4 = chunk & 31;
      float4 v = *(const float4*)(W + (long)(k0 + r) * 512 + n0 + c4 * 4);
      Bs[c4 * 4 + 0][r] = f2bf(v.x);
      Bs[c4 * 4 + 1][r] = f2bf(v.y);
      Bs[c4 * 4 + 2][r] = f2bf(v.z);
      Bs[c4 * 4 + 3][r] = f2bf(v.w);
    }
    __syncthreads();

    bf16x8 af[4], bfr[4];
#pragma unroll
    for (int mi = 0; mi < 4; ++mi)
      af[mi] = *(const bf16x8*)&As[waveM * 64 + mi * 16 + col][quad * 8];
#pragma unroll
    for (int ni = 0; ni < 4; ++ni)
      bfr[ni] = *(const bf16x8*)&Bs[waveN * 64 + ni * 16 + col][quad * 8];
#pragma unroll
    for (int mi = 0; mi < 4; ++mi)
#pragma unroll
      for (int ni = 0; ni < 4; ++ni)
        acc[mi][ni] = __builtin_amdgcn_mfma_f32_16x16x32_bf16(
            af[mi], bfr[ni], acc[mi][ni], 0, 0, 0);
  }

#pragma unroll
  for (int ni = 0; ni < 4; ++ni) {
    const int gn = n0 + waveN * 64 + ni * 16 + col;
    const float bv = bias[gn];
#pragma unroll
    for (int mi = 0; mi < 4; ++mi) {
#pragma unroll
      for (int r = 0; r < 4; ++r) {
        const int gm = m0 + waveM * 64 + mi * 16 + quad * 4 + r;
        const float val = acc[mi][ni][r] + bv;
        if constexpr (HEADS_OUT) {
          const int b_ = gm >> 9, s_ = gm & 511, h_ = gn >> 6, dk_ = gn & 63;
          ((unsigned short*)outv)[(((long)(b_ * 8 + h_)) * 512 + s_) * 64 + dk_] =
              f2bf(val);
        } else {
          ((float*)outv)[(long)gm * 512 + gn] = val;
        }
      }
    }
  }
}

// ---------------------------------------------------------------------------
// attn_sel v3: block = (128-row i-tile, bh), 512 threads (8 waves).
// Wave w computes the 16-row MFMA strip rows i0+w*16.. (4-term f16-split,
// same op order as the passing r4 kernel -> identical selection numerics).
// Scores -> LDS Ss[128][65]. Scan: thread = (row = tid&127, part = tid>>7);
// each thread scans a FIXED 16-column subset per tile, fully unrolled with
// loads batched into registers (kills the serial 120-cyc ds_read chain that
// dominated r4), streaming a private top-8. Final: per-row merge of 4x8
// candidates via padded LDS (stride 33, conflict-free) -> exact top-8.
// Weights (scale 0.125 applied at exp; exact pow2) written into own q row.
// ---------------------------------------------------------------------------
__global__ __launch_bounds__(512) void attn_sel_kernel(
    float* __restrict__ qh, const _Float16* __restrict__ khl,
    const int* __restrict__ kidx_ptr) {
  __shared__ __align__(16) char shbuf[33792];
  float (*Ss)[65] = (float(*)[65])shbuf;          // 128 x 65 fp32 = 33280 B
  float (*candv)[33] = (float(*)[33])shbuf;       // 128 x 33 fp32 = 16896 B
  int (*candi)[33] = (int(*)[33])(shbuf + 16896); // 128 x 33 i32  = 16896 B

  const int tid = threadIdx.x;
  const int lane = tid & 63, wave = tid >> 6;     // wave 0..7
  const int col16 = lane & 15, quad = lane >> 4;
  const int bh = blockIdx.y, ti = blockIdx.x;
  const int i0 = ti * 128;
  const int kidx = min(kidx_ptr[0], 8);

  const float* Qb = qh + (long)bh * 512 * 64;
  const _Float16* Kb = khl + (long)bh * 512 * 128;

  // A fragments: wave w covers rows i0 + w*16 + col16; k = c*32 + quad*8
  f16x8 ah[2], al[2];
#pragma unroll
  for (int c = 0; c < 2; ++c) {
    const float* p =
        Qb + (long)(i0 + wave * 16 + col16) * 64 + c * 32 + quad * 8;
    float4 x0 = *(const float4*)p, x1 = *(const float4*)(p + 4);
    float xs[8] = {x0.x, x0.y, x0.z, x0.w, x1.x, x1.y, x1.z, x1.w};
    f16x8 hv, lv;
#pragma unroll
    for (int e = 0; e < 8; ++e) {
      F16Pair pr = splitf(xs[e]);
      hv[e] = pr.hi; lv[e] = pr.lo;
    }
    ah[c] = hv; al[c] = lv;
  }

  const int row = tid & 127, part = tid >> 7;  // scan assignment
  const int i = i0 + row;

  float topv[8];
  int topi[8];
#pragma unroll
  for (int t = 0; t < 8; ++t) { topv[t] = -1e30f; topi[t] = 0; }
  float kth = -1e30f;

  const int ntiles = 2 * ti + 2;
  for (int t = 0; t < ntiles; ++t) {
    if (t > 0) __syncthreads();  // prior scan done reading Ss

    // ---- compute this wave's 16x64 score strip into LDS ----
    const _Float16* Kt = Kb + (long)t * 64 * 128;
#pragma unroll
    for (int ni = 0; ni < 4; ++ni) {
      f16x8 bhf[2], blf[2];
#pragma unroll
      for (int c = 0; c < 2; ++c) {
        const _Float16* p = Kt + (long)(ni * 16 + col16) * 128 + c * 32 + quad * 8;
        bhf[c] = *(const f16x8*)p;
        blf[c] = *(const f16x8*)(p + 64);
      }
      f32x4 a = (f32x4){0.f, 0.f, 0.f, 0.f};
#pragma unroll
      for (int c = 0; c < 2; ++c) {
        a = __builtin_amdgcn_mfma_f32_16x16x32_f16(al[c], blf[c], a, 0, 0, 0);
        a = __builtin_amdgcn_mfma_f32_16x16x32_f16(ah[c], blf[c], a, 0, 0, 0);
        a = __builtin_amdgcn_mfma_f32_16x16x32_f16(al[c], bhf[c], a, 0, 0, 0);
        a = __builtin_amdgcn_mfma_f32_16x16x32_f16(ah[c], bhf[c], a, 0, 0, 0);
      }
      const int row_l = wave * 16 + quad * 4;
      const int col_l = ni * 16 + col16;
#pragma unroll
      for (int r = 0; r < 4; ++r) Ss[row_l + r][col_l] = a[r];
    }
    __syncthreads();

    // ---- scan: batched loads, compile-time unrolled, causal-masked ----
    float sv[16];
#pragma unroll
    for (int cc = 0; cc < 16; ++cc) sv[cc] = Ss[row][part * 16 + cc];
    const int cbase = t * 64 + part * 16;
#pragma unroll
    for (int cc = 0; cc < 16; ++cc) {
      const float s = sv[cc];
      if (cbase + cc < i && s > kth) {
        float cv = s;
        int ci = cbase + cc;
#pragma unroll
        for (int u = 0; u < 8; ++u) {
          if (cv > topv[u]) {
            float tv = topv[u]; topv[u] = cv; cv = tv;
            int tix = topi[u]; topi[u] = ci; ci = tix;
          }
        }
#pragma unroll
        for (int u = 0; u < 8; ++u)
          if (u == kidx - 1) kth = topv[u];
      }
    }
  }

  // ---- deposit candidates (Ss no longer needed) ----
  __syncthreads();
#pragma unroll
  for (int u = 0; u < 8; ++u) {
    candv[row][part * 8 + u] = topv[u];
    candi[row][part * 8 + u] = topi[u];
  }
  __syncthreads();

  // ---- per-row merge of 32 candidates -> exact top-8, weights, write ----
  if (tid < 128) {
    float mv[8];
    int mi_[8];
#pragma unroll
    for (int u = 0; u < 8; ++u) { mv[u] = -1e30f; mi_[u] = 0; }
#pragma unroll
    for (int j = 0; j < 32; ++j) {
      float cv = candv[tid][j];
      int ci = candi[tid][j];
      if (cv > mv[7]) {
#pragma unroll
        for (int u = 0; u < 8; ++u) {
          if (cv > mv[u]) {
            float tv = mv[u]; mv[u] = cv; cv = tv;
            int tix = mi_[u]; mi_[u] = ci; ci = tix;
          }
        }
      }
    }

    const float m = mv[0];
    float w[8];
    float num = 0.f;
#pragma unroll
    for (int u = 0; u < 8; ++u) {
      const bool valid = (u < kidx) && (mv[u] > -1e29f);
      w[u] = valid ? expf((mv[u] - m) * 0.125f) : 0.f;
      num += w[u];
    }
    const float inv = (num > 0.f) ? 1.f / num : 0.f;  // row 0: zero weights

    float* Qrow = qh + ((long)bh * 512 + i0 + tid) * 64;
#pragma unroll
    for (int u = 0; u < 8; ++u) Qrow[u] = w[u] * inv;
    int* ip = (int*)Qrow;
#pragma unroll
    for (int u = 0; u < 8; ++u) ip[8 + u] = mi_[u];
  }
}

// ---------------------------------------------------------------------------
// gather: out_attn[row] = sum_t w_t * vh[idx_t]   (bf16 concat layout)
// ---------------------------------------------------------------------------
__global__ __launch_bounds__(256) void gather_kernel(
    const float* __restrict__ qh_sel, const unsigned short* __restrict__ vh,
    unsigned short* __restrict__ attn) {
  const int row = blockIdx.x * 256 + (int)threadIdx.x;  // [0, 131072)
  const int bh = row >> 9, i = row & 511;
  const int b = bh >> 3, h = bh & 7;

  const float* sel = qh_sel + (long)row * 64;
  const int* ip = (const int*)sel;

  float o[64];
#pragma unroll
  for (int d = 0; d < 64; ++d) o[d] = 0.f;

#pragma unroll
  for (int t = 0; t < 8; ++t) {
    const float w = sel[t];
    if (w != 0.f) {
      const unsigned short* Vrow = vh + ((long)bh * 512 + ip[8 + t]) * 64;
#pragma unroll
      for (int c = 0; c < 8; ++c) {
        uint4 raw = *(const uint4*)(Vrow + c * 8);
        float f[8];
        unpack8(raw, f);
#pragma unroll
        for (int d = 0; d < 8; ++d) o[c * 8 + d] = fmaf(w, f[d], o[c * 8 + d]);
      }
    }
  }

  const long ob = ((long)(b * 512 + i)) * 512 + h * 64;
#pragma unroll
  for (int c = 0; c < 8; ++c) {
    uint4 wv;
    wv.x = (unsigned)f2bf(o[c * 8 + 0]) | ((unsigned)f2bf(o[c * 8 + 1]) << 16);
    wv.y = (unsigned)f2bf(o[c * 8 + 2]) | ((unsigned)f2bf(o[c * 8 + 3]) << 16);
    wv.z = (unsigned)f2bf(o[c * 8 + 4]) | ((unsigned)f2bf(o[c * 8 + 5]) << 16);
    wv.w = (unsigned)f2bf(o[c * 8 + 6]) | ((unsigned)f2bf(o[c * 8 + 7]) << 16);
    *(uint4*)&attn[ob + c * 8] = wv;
  }
}

// ---------------------------------------------------------------------------
extern "C" void kernel_launch(void* const* d_in, const int* in_sizes, int n_in,
                              void* d_out, int out_size, void* d_ws, size_t ws_size,
                              hipStream_t stream) {
  const float* q   = (const float*)d_in[0];
  const float* k   = (const float*)d_in[1];
  const float* v   = (const float*)d_in[2];
  const float* w_q = (const float*)d_in[3];
  const float* b_q = (const float*)d_in[4];
  const float* w_k = (const float*)d_in[5];
  const float* b_k = (const float*)d_in[6];
  const float* w_v = (const float*)d_in[7];
  const float* b_v = (const float*)d_in[8];
  const float* w_o = (const float*)d_in[9];
  const float* b_o = (const float*)d_in[10];
  const int* kidx  = (const int*)d_in[11];

  // workspace (64 MiB): qh fp32 32M (also holds sel output) | khl f16-hilo
  // 32M. After attn_sel consumes khl, that region is reused for vh bf16
  // (16M) + attn bf16 (16M). Stream order makes the overlay safe.
  const long NE = (long)Bn * Hn * Sn * DKn;  // 8388608
  float* qh = (float*)d_ws;
  _Float16* khl = (_Float16*)(qh + NE);      // 131072 rows x 128 f16
  unsigned short* vh   = (unsigned short*)khl;
  unsigned short* attn = vh + NE;

  const dim3 gg(128, 4), bb(256);
  gemm_qk_kernel<<<dim3(128, 4, 2), bb, 0, stream>>>(q, w_q, b_q, qh,
                                                     k, w_k, b_k, khl);
  attn_sel_kernel<<<dim3(4, 256), dim3(512), 0, stream>>>(qh, khl, kidx);
  gemm_kernel<false, true><<<gg, bb, 0, stream>>>(v, w_v, b_v, vh);
  gather_kernel<<<512, bb, 0, stream>>>(qh, vh, attn);
  gemm_kernel<true, false><<<gg, bb, 0, stream>>>(attn, w_o, b_o, (float*)d_out);
}

// Round 6
// 698.146 us; speedup vs baseline: 1.2763x; 1.2763x over previous
//
#include <hip/hip_runtime.h>

// Problem constants (B,S,D,H fixed by reference)
constexpr int Bn = 32, Sn = 512, Dn = 512, Hn = 8, DKn = 64;

typedef __attribute__((ext_vector_type(8))) short bf16x8;
typedef __attribute__((ext_vector_type(8))) _Float16 f16x8;
typedef __attribute__((ext_vector_type(4))) _Float16 f16x4;
typedef __attribute__((ext_vector_type(4))) float f32x4;

#define DEV_INLINE __device__ __forceinline__

DEV_INLINE float bf2f(unsigned int u) { return __uint_as_float(u << 16); }

DEV_INLINE unsigned short f2bf(float f) {
  unsigned int u = __float_as_uint(f);
  u += 0x7fffu + ((u >> 16) & 1u);   // round-to-nearest-even; inputs finite
  return (unsigned short)(u >> 16);
}

DEV_INLINE void unpack8(const uint4 r, float* o) {
  o[0] = bf2f(r.x & 0xffffu); o[1] = bf2f(r.x >> 16);
  o[2] = bf2f(r.y & 0xffffu); o[3] = bf2f(r.y >> 16);
  o[4] = bf2f(r.z & 0xffffu); o[5] = bf2f(r.z >> 16);
  o[6] = bf2f(r.w & 0xffffu); o[7] = bf2f(r.w >> 16);
}

struct F16Pair { _Float16 hi, lo; };
DEV_INLINE F16Pair splitf(float x) {
  F16Pair p;
  p.hi = (_Float16)x;
  p.lo = (_Float16)(x - (float)p.hi);
  return p;
}

// ---------------------------------------------------------------------------
// Fused q+k projection: fp32-accurate GEMM via f16x2 split MFMA.
// blockIdx.z: z=0 -> q, fp32 heads [b,h,s,dk]; z=1 -> k, f16 hi/lo heads
// (row = (b*8+h)*512+s, 128 f16: [64 hi | 64 lo]).
// W pre-scaled by 64 at staging (keeps lo normal); epilogue rescales by 1/64.
// ---------------------------------------------------------------------------
__global__ __launch_bounds__(256) void gemm_qk_kernel(
    const float* __restrict__ Aq, const float* __restrict__ Wq,
    const float* __restrict__ bq, float* __restrict__ outq,
    const float* __restrict__ Ak, const float* __restrict__ Wk,
    const float* __restrict__ bk, _Float16* __restrict__ outk) {
  __shared__ _Float16 Ash[128][48], Asl[128][48];
  __shared__ _Float16 Bsh[128][48], Bsl[128][48];  // [n][k] transposed

  const int mode = blockIdx.z;
  const float* A = mode ? Ak : Aq;
  const float* W = mode ? Wk : Wq;
  const float* bias = mode ? bk : bq;

  const int m0 = blockIdx.x * 128, n0 = blockIdx.y * 128;
  const int tid  = threadIdx.x;
  const int lane = tid & 63, wave = tid >> 6;
  const int waveM = wave >> 1, waveN = wave & 1;
  const int col = lane & 15, quad = lane >> 4;

  f32x4 acc[4][4];
#pragma unroll
  for (int mi = 0; mi < 4; ++mi)
#pragma unroll
    for (int ni = 0; ni < 4; ++ni) acc[mi][ni] = (f32x4){0.f, 0.f, 0.f, 0.f};

  for (int k0 = 0; k0 < 512; k0 += 32) {
    __syncthreads();
#pragma unroll
    for (int it = 0; it < 4; ++it) {
      int chunk = tid + it * 256;            // 1024 float4 chunks (128x32)
      int r = chunk >> 3, c4 = chunk & 7;
      float4 v = *(const float4*)(A + (long)(m0 + r) * 512 + k0 + c4 * 4);
      F16Pair p0 = splitf(v.x), p1 = splitf(v.y),
              p2 = splitf(v.z), p3 = splitf(v.w);
      f16x4 hv = {p0.hi, p1.hi, p2.hi, p3.hi};
      f16x4 lv = {p0.lo, p1.lo, p2.lo, p3.lo};
      *(f16x4*)&Ash[r][c4 * 4] = hv;
      *(f16x4*)&Asl[r][c4 * 4] = lv;
    }
#pragma unroll
    for (int it = 0; it < 4; ++it) {
      int chunk = tid + it * 256;            // 32 k-rows x 32 n-chunks
      int r = chunk >> 5, c4 = chunk & 31;
      float4 v = *(const float4*)(W + (long)(k0 + r) * 512 + n0 + c4 * 4);
      F16Pair p0 = splitf(v.x * 64.f), p1 = splitf(v.y * 64.f),
              p2 = splitf(v.z * 64.f), p3 = splitf(v.w * 64.f);
      Bsh[c4 * 4 + 0][r] = p0.hi; Bsl[c4 * 4 + 0][r] = p0.lo;
      Bsh[c4 * 4 + 1][r] = p1.hi; Bsl[c4 * 4 + 1][r] = p1.lo;
      Bsh[c4 * 4 + 2][r] = p2.hi; Bsl[c4 * 4 + 2][r] = p2.lo;
      Bsh[c4 * 4 + 3][r] = p3.hi; Bsl[c4 * 4 + 3][r] = p3.lo;
    }
    __syncthreads();

    f16x8 ah[4], al[4], bh[4], bl[4];
#pragma unroll
    for (int mi = 0; mi < 4; ++mi) {
      ah[mi] = *(const f16x8*)&Ash[waveM * 64 + mi * 16 + col][quad * 8];
      al[mi] = *(const f16x8*)&Asl[waveM * 64 + mi * 16 + col][quad * 8];
    }
#pragma unroll
    for (int ni = 0; ni < 4; ++ni) {
      bh[ni] = *(const f16x8*)&Bsh[waveN * 64 + ni * 16 + col][quad * 8];
      bl[ni] = *(const f16x8*)&Bsl[waveN * 64 + ni * 16 + col][quad * 8];
    }
#pragma unroll
    for (int mi = 0; mi < 4; ++mi)
#pragma unroll
      for (int ni = 0; ni < 4; ++ni) {
        acc[mi][ni] = __builtin_amdgcn_mfma_f32_16x16x32_f16(
            ah[mi], bl[ni], acc[mi][ni], 0, 0, 0);
        acc[mi][ni] = __builtin_amdgcn_mfma_f32_16x16x32_f16(
            al[mi], bh[ni], acc[mi][ni], 0, 0, 0);
        acc[mi][ni] = __builtin_amdgcn_mfma_f32_16x16x32_f16(
            ah[mi], bh[ni], acc[mi][ni], 0, 0, 0);
      }
  }

  // C/D layout: col=lane&15, row=quad*4+reg (m89/m91-verified)
#pragma unroll
  for (int ni = 0; ni < 4; ++ni) {
    const int gn = n0 + waveN * 64 + ni * 16 + col;
    const float bv = bias[gn];
    const int h_ = gn >> 6, dk_ = gn & 63;
#pragma unroll
    for (int mi = 0; mi < 4; ++mi) {
#pragma unroll
      for (int r = 0; r < 4; ++r) {
        const int gm = m0 + waveM * 64 + mi * 16 + quad * 4 + r;
        const int b_ = gm >> 9, s_ = gm & 511;
        const long row = (long)(b_ * 8 + h_) * 512 + s_;
        const float val = acc[mi][ni][r] * 0.015625f + bv;
        if (mode == 0) {
          outq[row * 64 + dk_] = val;
        } else {
          F16Pair p = splitf(val);
          outk[row * 128 + dk_]      = p.hi;
          outk[row * 128 + 64 + dk_] = p.lo;
        }
      }
    }
  }
}

// ---------------------------------------------------------------------------
// bf16 MFMA GEMM (for v-projection and out-projection; continuous-error path)
// ---------------------------------------------------------------------------
template <bool A_IS_BF16, bool HEADS_OUT>
__global__ __launch_bounds__(256) void gemm_kernel(
    const void* __restrict__ Av, const float* __restrict__ W,
    const float* __restrict__ bias, void* __restrict__ outv) {
  __shared__ unsigned short As[128][48];
  __shared__ unsigned short Bs[128][48];  // [n][k]

  const int m0 = blockIdx.x * 128, n0 = blockIdx.y * 128;
  const int tid  = threadIdx.x;
  const int lane = tid & 63, wave = tid >> 6;
  const int waveM = wave >> 1, waveN = wave & 1;
  const int col = lane & 15, quad = lane >> 4;

  f32x4 acc[4][4];
#pragma unroll
  for (int mi = 0; mi < 4; ++mi)
#pragma unroll
    for (int ni = 0; ni < 4; ++ni) acc[mi][ni] = (f32x4){0.f, 0.f, 0.f, 0.f};

  for (int k0 = 0; k0 < 512; k0 += 32) {
    __syncthreads();
    if constexpr (!A_IS_BF16) {
      const float* A = (const float*)Av;
#pragma unroll
      for (int it = 0; it < 4; ++it) {
        int chunk = tid + it * 256;
        int r = chunk >> 3, c4 = chunk & 7;
        float4 v = *(const float4*)(A + (long)(m0 + r) * 512 + k0 + c4 * 4);
        ushort4 w;
        w.x = f2bf(v.x); w.y = f2bf(v.y); w.z = f2bf(v.z); w.w = f2bf(v.w);
        *(ushort4*)&As[r][c4 * 4] = w;
      }
    } else {
      const unsigned short* A = (const unsigned short*)Av;
#pragma unroll
      for (int it = 0; it < 2; ++it) {
        int chunk = tid + it * 256;
        int r = chunk >> 2, c8 = chunk & 3;
        uint4 v = *(const uint4*)(A + (long)(m0 + r) * 512 + k0 + c8 * 8);
        *(uint4*)&As[r][c8 * 8] = v;
      }
    }
#pragma unroll
    for (int it = 0; it < 4; ++it) {
      int chunk = tid + it * 256;
      int r = chunk >> 5, c4 = chunk & 31;
      float4 v = *(const float4*)(W + (long)(k0 + r) * 512 + n0 + c4 * 4);
      Bs[c4 * 4 + 0][r] = f2bf(v.x);
      Bs[c4 * 4 + 1][r] = f2bf(v.y);
      Bs[c4 * 4 + 2][r] = f2bf(v.z);
      Bs[c4 * 4 + 3][r] = f2bf(v.w);
    }
    __syncthreads();

    bf16x8 af[4], bfr[4];
#pragma unroll
    for (int mi = 0; mi < 4; ++mi)
      af[mi] = *(const bf16x8*)&As[waveM * 64 + mi * 16 + col][quad * 8];
#pragma unroll
    for (int ni = 0; ni < 4; ++ni)
      bfr[ni] = *(const bf16x8*)&Bs[waveN * 64 + ni * 16 + col][quad * 8];
#pragma unroll
    for (int mi = 0; mi < 4; ++mi)
#pragma unroll
      for (int ni = 0; ni < 4; ++ni)
        acc[mi][ni] = __builtin_amdgcn_mfma_f32_16x16x32_bf16(
            af[mi], bfr[ni], acc[mi][ni], 0, 0, 0);
  }

#pragma unroll
  for (int ni = 0; ni < 4; ++ni) {
    const int gn = n0 + waveN * 64 + ni * 16 + col;
    const float bv = bias[gn];
#pragma unroll
    for (int mi = 0; mi < 4; ++mi) {
#pragma unroll
      for (int r = 0; r < 4; ++r) {
        const int gm = m0 + waveM * 64 + mi * 16 + quad * 4 + r;
        const float val = acc[mi][ni][r] + bv;
        if constexpr (HEADS_OUT) {
          const int b_ = gm >> 9, s_ = gm & 511, h_ = gn >> 6, dk_ = gn & 63;
          ((unsigned short*)outv)[(((long)(b_ * 8 + h_)) * 512 + s_) * 64 + dk_] =
              f2bf(val);
        } else {
          ((float*)outv)[(long)gm * 512 + gn] = val;
        }
      }
    }
  }
}

// ---------------------------------------------------------------------------
// attn_sel v4: PERFECTLY BALANCED blocks. Grid (2, 256): block p handles
// i-tile pair p=0 -> {0,3}, p=1 -> {1,2} — every block does exactly 10
// 64-col tile-iters (fixes the r5 4x CU-load aliasing: ti = blockid&3 put 4
// same-ti blocks on each CU -> 25% occupancy, 4x tail).
// Per i-tile: 8 waves, wave w computes the 16-row MFMA strip (4-term
// f16-split, same op order as the passing r4/r5 kernels -> identical
// numerics) into Ss[128][65]; next tile's 16 B-frags are PREFETCHED into
// registers right after the MFMAs so the ~400-cyc global latency overlaps
// the scan+barrier instead of heading the critical path. Scan: thread =
// (row=tid&127, part=tid>>7), fixed 16-col subset per tile, batched loads,
// private streaming top-8; final per-row merge of 4x8 candidates -> exact
// top-8; weights (0.125 scale at exp; exact pow2) written into own q row.
// ---------------------------------------------------------------------------
__global__ __launch_bounds__(512, 4) void attn_sel_kernel(
    float* __restrict__ qh, const _Float16* __restrict__ khl,
    const int* __restrict__ kidx_ptr) {
  __shared__ __align__(16) char shbuf[33792];
  float (*Ss)[65] = (float(*)[65])shbuf;          // 128 x 65 fp32 = 33280 B
  float (*candv)[33] = (float(*)[33])shbuf;       // 128 x 33 fp32 = 16896 B
  int (*candi)[33] = (int(*)[33])(shbuf + 16896); // 128 x 33 i32  = 16896 B

  const int tid = threadIdx.x;
  const int lane = tid & 63, wave = tid >> 6;     // wave 0..7
  const int col16 = lane & 15, quad = lane >> 4;
  const int bh = blockIdx.y, p = blockIdx.x;
  const int kidx = min(kidx_ptr[0], 8);

  const float* Qb = qh + (long)bh * 512 * 64;
  const _Float16* Kb = khl + (long)bh * 512 * 128;

  const int row = tid & 127, part = tid >> 7;  // scan assignment

#pragma unroll
  for (int s = 0; s < 2; ++s) {
    const int ti = (s == 0) ? (p == 0 ? 0 : 1) : (p == 0 ? 3 : 2);
    const int i0 = ti * 128;
    const int i = i0 + row;
    const int ntiles = 2 * ti + 2;

    // A fragments: wave w covers rows i0 + w*16 + col16; k = c*32 + quad*8
    f16x8 ah[2], al[2];
#pragma unroll
    for (int c = 0; c < 2; ++c) {
      const float* ptr =
          Qb + (long)(i0 + wave * 16 + col16) * 64 + c * 32 + quad * 8;
      float4 x0 = *(const float4*)ptr, x1 = *(const float4*)(ptr + 4);
      float xs[8] = {x0.x, x0.y, x0.z, x0.w, x1.x, x1.y, x1.z, x1.w};
      f16x8 hv, lv;
#pragma unroll
      for (int e = 0; e < 8; ++e) {
        F16Pair pr = splitf(xs[e]);
        hv[e] = pr.hi; lv[e] = pr.lo;
      }
      ah[c] = hv; al[c] = lv;
    }

    float topv[8];
    int topi[8];
#pragma unroll
    for (int t = 0; t < 8; ++t) { topv[t] = -1e30f; topi[t] = 0; }
    float kth = -1e30f;

    // preload tile-0 B-frags (16 x f16x8 = 64 VGPRs)
    f16x8 pb[16];
#pragma unroll
    for (int ni = 0; ni < 4; ++ni)
#pragma unroll
      for (int c = 0; c < 2; ++c) {
        const _Float16* ptr = Kb + (long)(ni * 16 + col16) * 128 + c * 32 + quad * 8;
        pb[ni * 4 + c * 2 + 0] = *(const f16x8*)ptr;
        pb[ni * 4 + c * 2 + 1] = *(const f16x8*)(ptr + 64);
      }

    for (int t = 0; t < ntiles; ++t) {
      __syncthreads();  // prior scan / prior i-tile merge done with shbuf

      // ---- strip compute from prefetched frags ----
#pragma unroll
      for (int ni = 0; ni < 4; ++ni) {
        f32x4 a = (f32x4){0.f, 0.f, 0.f, 0.f};
#pragma unroll
        for (int c = 0; c < 2; ++c) {
          const f16x8 bhf = pb[ni * 4 + c * 2], blf = pb[ni * 4 + c * 2 + 1];
          a = __builtin_amdgcn_mfma_f32_16x16x32_f16(al[c], blf, a, 0, 0, 0);
          a = __builtin_amdgcn_mfma_f32_16x16x32_f16(ah[c], blf, a, 0, 0, 0);
          a = __builtin_amdgcn_mfma_f32_16x16x32_f16(al[c], bhf, a, 0, 0, 0);
          a = __builtin_amdgcn_mfma_f32_16x16x32_f16(ah[c], bhf, a, 0, 0, 0);
        }
        const int row_l = wave * 16 + quad * 4;
        const int col_l = ni * 16 + col16;
#pragma unroll
        for (int r = 0; r < 4; ++r) Ss[row_l + r][col_l] = a[r];
      }

      // ---- prefetch next tile's B-frags (in flight during scan+barrier) ----
      if (t + 1 < ntiles) {
        const _Float16* Kt = Kb + (long)(t + 1) * 64 * 128;
#pragma unroll
        for (int ni = 0; ni < 4; ++ni)
#pragma unroll
          for (int c = 0; c < 2; ++c) {
            const _Float16* ptr =
                Kt + (long)(ni * 16 + col16) * 128 + c * 32 + quad * 8;
            pb[ni * 4 + c * 2 + 0] = *(const f16x8*)ptr;
            pb[ni * 4 + c * 2 + 1] = *(const f16x8*)(ptr + 64);
          }
      }
      __syncthreads();

      // ---- scan: two 8-col batches, compile-time unrolled, causal-masked --
      const int cbase = t * 64 + part * 16;
#pragma unroll
      for (int half = 0; half < 2; ++half) {
        float sv[8];
#pragma unroll
        for (int cc = 0; cc < 8; ++cc)
          sv[cc] = Ss[row][part * 16 + half * 8 + cc];
#pragma unroll
        for (int cc = 0; cc < 8; ++cc) {
          const float sc = sv[cc];
          const int ci0 = cbase + half * 8 + cc;
          if (ci0 < i && sc > kth) {
            float cv = sc;
            int ci = ci0;
#pragma unroll
            for (int u = 0; u < 8; ++u) {
              if (cv > topv[u]) {
                float tv = topv[u]; topv[u] = cv; cv = tv;
                int tix = topi[u]; topi[u] = ci; ci = tix;
              }
            }
#pragma unroll
            for (int u = 0; u < 8; ++u)
              if (u == kidx - 1) kth = topv[u];
          }
        }
      }
    }

    // ---- deposit candidates (Ss no longer needed) ----
    __syncthreads();
#pragma unroll
    for (int u = 0; u < 8; ++u) {
      candv[row][part * 8 + u] = topv[u];
      candi[row][part * 8 + u] = topi[u];
    }
    __syncthreads();

    // ---- per-row merge of 32 candidates -> exact top-8, weights, write ----
    if (tid < 128) {
      float mv[8];
      int mi_[8];
#pragma unroll
      for (int u = 0; u < 8; ++u) { mv[u] = -1e30f; mi_[u] = 0; }
#pragma unroll
      for (int j = 0; j < 32; ++j) {
        float cv = candv[tid][j];
        int ci = candi[tid][j];
        if (cv > mv[7]) {
#pragma unroll
          for (int u = 0; u < 8; ++u) {
            if (cv > mv[u]) {
              float tv = mv[u]; mv[u] = cv; cv = tv;
              int tix = mi_[u]; mi_[u] = ci; ci = tix;
            }
          }
        }
      }

      const float m = mv[0];
      float w[8];
      float num = 0.f;
#pragma unroll
      for (int u = 0; u < 8; ++u) {
        const bool valid = (u < kidx) && (mv[u] > -1e29f);
        w[u] = valid ? expf((mv[u] - m) * 0.125f) : 0.f;
        num += w[u];
      }
      const float inv = (num > 0.f) ? 1.f / num : 0.f;  // row 0: zero weights

      float* Qrow = qh + ((long)bh * 512 + i0 + tid) * 64;
#pragma unroll
      for (int u = 0; u < 8; ++u) Qrow[u] = w[u] * inv;
      int* ip = (int*)Qrow;
#pragma unroll
      for (int u = 0; u < 8; ++u) ip[8 + u] = mi_[u];
    }
    // next i-tile's first loop-top __syncthreads() protects shbuf reuse
  }
}

// ---------------------------------------------------------------------------
// gather: out_attn[row] = sum_t w_t * vh[idx_t]   (bf16 concat layout)
// ---------------------------------------------------------------------------
__global__ __launch_bounds__(256) void gather_kernel(
    const float* __restrict__ qh_sel, const unsigned short* __restrict__ vh,
    unsigned short* __restrict__ attn) {
  const int row = blockIdx.x * 256 + (int)threadIdx.x;  // [0, 131072)
  const int bh = row >> 9, i = row & 511;
  const int b = bh >> 3, h = bh & 7;

  const float* sel = qh_sel + (long)row * 64;
  const int* ip = (const int*)sel;

  float o[64];
#pragma unroll
  for (int d = 0; d < 64; ++d) o[d] = 0.f;

#pragma unroll
  for (int t = 0; t < 8; ++t) {
    const float w = sel[t];
    if (w != 0.f) {
      const unsigned short* Vrow = vh + ((long)bh * 512 + ip[8 + t]) * 64;
#pragma unroll
      for (int c = 0; c < 8; ++c) {
        uint4 raw = *(const uint4*)(Vrow + c * 8);
        float f[8];
        unpack8(raw, f);
#pragma unroll
        for (int d = 0; d < 8; ++d) o[c * 8 + d] = fmaf(w, f[d], o[c * 8 + d]);
      }
    }
  }

  const long ob = ((long)(b * 512 + i)) * 512 + h * 64;
#pragma unroll
  for (int c = 0; c < 8; ++c) {
    uint4 wv;
    wv.x = (unsigned)f2bf(o[c * 8 + 0]) | ((unsigned)f2bf(o[c * 8 + 1]) << 16);
    wv.y = (unsigned)f2bf(o[c * 8 + 2]) | ((unsigned)f2bf(o[c * 8 + 3]) << 16);
    wv.z = (unsigned)f2bf(o[c * 8 + 4]) | ((unsigned)f2bf(o[c * 8 + 5]) << 16);
    wv.w = (unsigned)f2bf(o[c * 8 + 6]) | ((unsigned)f2bf(o[c * 8 + 7]) << 16);
    *(uint4*)&attn[ob + c * 8] = wv;
  }
}

// ---------------------------------------------------------------------------
extern "C" void kernel_launch(void* const* d_in, const int* in_sizes, int n_in,
                              void* d_out, int out_size, void* d_ws, size_t ws_size,
                              hipStream_t stream) {
  const float* q   = (const float*)d_in[0];
  const float* k   = (const float*)d_in[1];
  const float* v   = (const float*)d_in[2];
  const float* w_q = (const float*)d_in[3];
  const float* b_q = (const float*)d_in[4];
  const float* w_k = (const float*)d_in[5];
  const float* b_k = (const float*)d_in[6];
  const float* w_v = (const float*)d_in[7];
  const float* b_v = (const float*)d_in[8];
  const float* w_o = (const float*)d_in[9];
  const float* b_o = (const float*)d_in[10];
  const int* kidx  = (const int*)d_in[11];

  // workspace (64 MiB): qh fp32 32M (also holds sel output) | khl f16-hilo
  // 32M. After attn_sel consumes khl, that region is reused for vh bf16
  // (16M) + attn bf16 (16M). Stream order makes the overlay safe.
  const long NE = (long)Bn * Hn * Sn * DKn;  // 8388608
  float* qh = (float*)d_ws;
  _Float16* khl = (_Float16*)(qh + NE);      // 131072 rows x 128 f16
  unsigned short* vh   = (unsigned short*)khl;
  unsigned short* attn = vh + NE;

  const dim3 gg(128, 4), bb(256);
  gemm_qk_kernel<<<dim3(128, 4, 2), bb, 0, stream>>>(q, w_q, b_q, qh,
                                                     k, w_k, b_k, khl);
  attn_sel_kernel<<<dim3(2, 256), dim3(512), 0, stream>>>(qh, khl, kidx);
  gemm_kernel<false, true><<<gg, bb, 0, stream>>>(v, w_v, b_v, vh);
  gather_kernel<<<512, bb, 0, stream>>>(qh, vh, attn);
  gemm_kernel<true, false><<<gg, bb, 0, stream>>>(attn, w_o, b_o, (float*)d_out);
}

// Round 7
// 469.646 us; speedup vs baseline: 1.8973x; 1.4865x over previous
//
#include <hip/hip_runtime.h>

// Problem constants (B,S,D,H fixed by reference)
constexpr int Bn = 32, Sn = 512, Dn = 512, Hn = 8, DKn = 64;

typedef __attribute__((ext_vector_type(8))) short bf16x8;
typedef __attribute__((ext_vector_type(8))) _Float16 f16x8;
typedef __attribute__((ext_vector_type(4))) _Float16 f16x4;
typedef __attribute__((ext_vector_type(4))) float f32x4;

#define DEV_INLINE __device__ __forceinline__

DEV_INLINE float bf2f(unsigned int u) { return __uint_as_float(u << 16); }

DEV_INLINE unsigned short f2bf(float f) {
  unsigned int u = __float_as_uint(f);
  u += 0x7fffu + ((u >> 16) & 1u);   // round-to-nearest-even; inputs finite
  return (unsigned short)(u >> 16);
}

DEV_INLINE void unpack8(const uint4 r, float* o) {
  o[0] = bf2f(r.x & 0xffffu); o[1] = bf2f(r.x >> 16);
  o[2] = bf2f(r.y & 0xffffu); o[3] = bf2f(r.y >> 16);
  o[4] = bf2f(r.z & 0xffffu); o[5] = bf2f(r.z >> 16);
  o[6] = bf2f(r.w & 0xffffu); o[7] = bf2f(r.w >> 16);
}

struct F16Pair { _Float16 hi, lo; };
DEV_INLINE F16Pair splitf(float x) {
  F16Pair p;
  p.hi = (_Float16)x;
  p.lo = (_Float16)(x - (float)p.hi);
  return p;
}

// LDS row stride: 40 elems (80 B = 20 words). gcd(20,32)=4 -> frag b128
// reads spread evenly over all 32 banks; 80 % 16 == 0 keeps b128 aligned.
// (r6 used 48 -> 24 words, gcd 8: 32-way conflicts on B-staging writes =
// 1.32e8 conflict cycles = ~75% of gemm_qk's time.)
constexpr int LDW = 40;

// ---------------------------------------------------------------------------
// Fused q+k projection: fp32-accurate GEMM via f16x2 split MFMA.
// blockIdx.z: z=0 -> q, fp32 heads [b,h,s,dk]; z=1 -> k, f16 hi/lo heads
// (row = (b*8+h)*512+s, 128 f16: [64 hi | 64 lo]).
// W pre-scaled by 64 at staging (keeps lo normal); epilogue rescales by 1/64.
// B-staging is n-major: thread owns one n-row x 16 k; coalesced dword reads,
// b64 row-writes (2-way bank = free).
// ---------------------------------------------------------------------------
__global__ __launch_bounds__(256) void gemm_qk_kernel(
    const float* __restrict__ Aq, const float* __restrict__ Wq,
    const float* __restrict__ bq, float* __restrict__ outq,
    const float* __restrict__ Ak, const float* __restrict__ Wk,
    const float* __restrict__ bk, _Float16* __restrict__ outk) {
  __shared__ _Float16 Ash[128][LDW], Asl[128][LDW];
  __shared__ _Float16 Bsh[128][LDW], Bsl[128][LDW];  // [n][k] transposed

  const int mode = blockIdx.z;
  const float* A = mode ? Ak : Aq;
  const float* W = mode ? Wk : Wq;
  const float* bias = mode ? bk : bq;

  const int m0 = blockIdx.x * 128, n0 = blockIdx.y * 128;
  const int tid  = threadIdx.x;
  const int lane = tid & 63, wave = tid >> 6;
  const int waveM = wave >> 1, waveN = wave & 1;
  const int col = lane & 15, quad = lane >> 4;

  // B-staging assignment: one n-row, 16 k's
  const int bn = tid & 127, brh = tid >> 7;  // brh in {0,1}

  f32x4 acc[4][4];
#pragma unroll
  for (int mi = 0; mi < 4; ++mi)
#pragma unroll
    for (int ni = 0; ni < 4; ++ni) acc[mi][ni] = (f32x4){0.f, 0.f, 0.f, 0.f};

  for (int k0 = 0; k0 < 512; k0 += 32) {
    __syncthreads();
    // A: 128 m x 32 k, float4 reads, b64 LDS writes (conflict-free @ LDW=40)
#pragma unroll
    for (int it = 0; it < 4; ++it) {
      int chunk = tid + it * 256;            // 1024 float4 chunks (128x32)
      int r = chunk >> 3, c4 = chunk & 7;
      float4 v = *(const float4*)(A + (long)(m0 + r) * 512 + k0 + c4 * 4);
      F16Pair p0 = splitf(v.x), p1 = splitf(v.y),
              p2 = splitf(v.z), p3 = splitf(v.w);
      f16x4 hv = {p0.hi, p1.hi, p2.hi, p3.hi};
      f16x4 lv = {p0.lo, p1.lo, p2.lo, p3.lo};
      *(f16x4*)&Ash[r][c4 * 4] = hv;
      *(f16x4*)&Asl[r][c4 * 4] = lv;
    }
    // B: n-major; 16 coalesced dword reads (lanes = consecutive n), scaled
    // split, 4x b64 writes along own row.
    {
      _Float16 h16[16], l16[16];
#pragma unroll
      for (int kk = 0; kk < 16; ++kk) {
        float w = W[(long)(k0 + brh * 16 + kk) * 512 + n0 + bn] * 64.f;
        F16Pair p = splitf(w);
        h16[kk] = p.hi; l16[kk] = p.lo;
      }
#pragma unroll
      for (int g = 0; g < 4; ++g) {
        f16x4 hv = {h16[g * 4], h16[g * 4 + 1], h16[g * 4 + 2], h16[g * 4 + 3]};
        f16x4 lv = {l16[g * 4], l16[g * 4 + 1], l16[g * 4 + 2], l16[g * 4 + 3]};
        *(f16x4*)&Bsh[bn][brh * 16 + g * 4] = hv;
        *(f16x4*)&Bsl[bn][brh * 16 + g * 4] = lv;
      }
    }
    __syncthreads();

    f16x8 ah[4], al[4], bh[4], bl[4];
#pragma unroll
    for (int mi = 0; mi < 4; ++mi) {
      ah[mi] = *(const f16x8*)&Ash[waveM * 64 + mi * 16 + col][quad * 8];
      al[mi] = *(const f16x8*)&Asl[waveM * 64 + mi * 16 + col][quad * 8];
    }
#pragma unroll
    for (int ni = 0; ni < 4; ++ni) {
      bh[ni] = *(const f16x8*)&Bsh[waveN * 64 + ni * 16 + col][quad * 8];
      bl[ni] = *(const f16x8*)&Bsl[waveN * 64 + ni * 16 + col][quad * 8];
    }
#pragma unroll
    for (int mi = 0; mi < 4; ++mi)
#pragma unroll
      for (int ni = 0; ni < 4; ++ni) {
        acc[mi][ni] = __builtin_amdgcn_mfma_f32_16x16x32_f16(
            ah[mi], bl[ni], acc[mi][ni], 0, 0, 0);
        acc[mi][ni] = __builtin_amdgcn_mfma_f32_16x16x32_f16(
            al[mi], bh[ni], acc[mi][ni], 0, 0, 0);
        acc[mi][ni] = __builtin_amdgcn_mfma_f32_16x16x32_f16(
            ah[mi], bh[ni], acc[mi][ni], 0, 0, 0);
      }
  }

  // C/D layout: col=lane&15, row=quad*4+reg (m89/m91-verified)
#pragma unroll
  for (int ni = 0; ni < 4; ++ni) {
    const int gn = n0 + waveN * 64 + ni * 16 + col;
    const float bv = bias[gn];
    const int h_ = gn >> 6, dk_ = gn & 63;
#pragma unroll
    for (int mi = 0; mi < 4; ++mi) {
#pragma unroll
      for (int r = 0; r < 4; ++r) {
        const int gm = m0 + waveM * 64 + mi * 16 + quad * 4 + r;
        const int b_ = gm >> 9, s_ = gm & 511;
        const long row = (long)(b_ * 8 + h_) * 512 + s_;
        const float val = acc[mi][ni][r] * 0.015625f + bv;
        if (mode == 0) {
          outq[row * 64 + dk_] = val;
        } else {
          F16Pair p = splitf(val);
          outk[row * 128 + dk_]      = p.hi;
          outk[row * 128 + 64 + dk_] = p.lo;
        }
      }
    }
  }
}

// ---------------------------------------------------------------------------
// bf16 MFMA GEMM (for v-projection and out-projection; continuous-error path)
// Same conflict-free staging: LDW=40, n-major B-staging.
// ---------------------------------------------------------------------------
template <bool A_IS_BF16, bool HEADS_OUT>
__global__ __launch_bounds__(256) void gemm_kernel(
    const void* __restrict__ Av, const float* __restrict__ W,
    const float* __restrict__ bias, void* __restrict__ outv) {
  __shared__ unsigned short As[128][LDW];
  __shared__ unsigned short Bs[128][LDW];  // [n][k]

  const int m0 = blockIdx.x * 128, n0 = blockIdx.y * 128;
  const int tid  = threadIdx.x;
  const int lane = tid & 63, wave = tid >> 6;
  const int waveM = wave >> 1, waveN = wave & 1;
  const int col = lane & 15, quad = lane >> 4;

  const int bn = tid & 127, brh = tid >> 7;

  f32x4 acc[4][4];
#pragma unroll
  for (int mi = 0; mi < 4; ++mi)
#pragma unroll
    for (int ni = 0; ni < 4; ++ni) acc[mi][ni] = (f32x4){0.f, 0.f, 0.f, 0.f};

  for (int k0 = 0; k0 < 512; k0 += 32) {
    __syncthreads();
    if constexpr (!A_IS_BF16) {
      const float* A = (const float*)Av;
#pragma unroll
      for (int it = 0; it < 4; ++it) {
        int chunk = tid + it * 256;
        int r = chunk >> 3, c4 = chunk & 7;
        float4 v = *(const float4*)(A + (long)(m0 + r) * 512 + k0 + c4 * 4);
        ushort4 w;
        w.x = f2bf(v.x); w.y = f2bf(v.y); w.z = f2bf(v.z); w.w = f2bf(v.w);
        *(ushort4*)&As[r][c4 * 4] = w;
      }
    } else {
      const unsigned short* A = (const unsigned short*)Av;
#pragma unroll
      for (int it = 0; it < 2; ++it) {
        int chunk = tid + it * 256;
        int r = chunk >> 2, c8 = chunk & 3;
        uint4 v = *(const uint4*)(A + (long)(m0 + r) * 512 + k0 + c8 * 8);
        *(uint4*)&As[r][c8 * 8] = v;
      }
    }
    // B: n-major staging (conflict-free)
    {
      unsigned short h16[16];
#pragma unroll
      for (int kk = 0; kk < 16; ++kk)
        h16[kk] = f2bf(W[(long)(k0 + brh * 16 + kk) * 512 + n0 + bn]);
#pragma unroll
      for (int g = 0; g < 4; ++g) {
        ushort4 hv = {h16[g * 4], h16[g * 4 + 1], h16[g * 4 + 2], h16[g * 4 + 3]};
        *(ushort4*)&Bs[bn][brh * 16 + g * 4] = hv;
      }
    }
    __syncthreads();

    bf16x8 af[4], bfr[4];
#pragma unroll
    for (int mi = 0; mi < 4; ++mi)
      af[mi] = *(const bf16x8*)&As[waveM * 64 + mi * 16 + col][quad * 8];
#pragma unroll
    for (int ni = 0; ni < 4; ++ni)
      bfr[ni] = *(const bf16x8*)&Bs[waveN * 64 + ni * 16 + col][quad * 8];
#pragma unroll
    for (int mi = 0; mi < 4; ++mi)
#pragma unroll
      for (int ni = 0; ni < 4; ++ni)
        acc[mi][ni] = __builtin_amdgcn_mfma_f32_16x16x32_bf16(
            af[mi], bfr[ni], acc[mi][ni], 0, 0, 0);
  }

#pragma unroll
  for (int ni = 0; ni < 4; ++ni) {
    const int gn = n0 + waveN * 64 + ni * 16 + col;
    const float bv = bias[gn];
#pragma unroll
    for (int mi = 0; mi < 4; ++mi) {
#pragma unroll
      for (int r = 0; r < 4; ++r) {
        const int gm = m0 + waveM * 64 + mi * 16 + quad * 4 + r;
        const float val = acc[mi][ni][r] + bv;
        if constexpr (HEADS_OUT) {
          const int b_ = gm >> 9, s_ = gm & 511, h_ = gn >> 6, dk_ = gn & 63;
          ((unsigned short*)outv)[(((long)(b_ * 8 + h_)) * 512 + s_) * 64 + dk_] =
              f2bf(val);
        } else {
          ((float*)outv)[(long)gm * 512 + gn] = val;
        }
      }
    }
  }
}

// ---------------------------------------------------------------------------
// attn_sel v4 (unchanged from r6): balanced block pairs {0,3}/{1,2}, 8-wave
// MFMA strips with register B-frag prefetch, partitioned unrolled scan,
// exact per-row merge. Numerics identical to the r4/r5/r6 passing kernels.
// ---------------------------------------------------------------------------
__global__ __launch_bounds__(512, 4) void attn_sel_kernel(
    float* __restrict__ qh, const _Float16* __restrict__ khl,
    const int* __restrict__ kidx_ptr) {
  __shared__ __align__(16) char shbuf[33792];
  float (*Ss)[65] = (float(*)[65])shbuf;          // 128 x 65 fp32 = 33280 B
  float (*candv)[33] = (float(*)[33])shbuf;       // 128 x 33 fp32 = 16896 B
  int (*candi)[33] = (int(*)[33])(shbuf + 16896); // 128 x 33 i32  = 16896 B

  const int tid = threadIdx.x;
  const int lane = tid & 63, wave = tid >> 6;     // wave 0..7
  const int col16 = lane & 15, quad = lane >> 4;
  const int bh = blockIdx.y, p = blockIdx.x;
  const int kidx = min(kidx_ptr[0], 8);

  const float* Qb = qh + (long)bh * 512 * 64;
  const _Float16* Kb = khl + (long)bh * 512 * 128;

  const int row = tid & 127, part = tid >> 7;  // scan assignment

#pragma unroll
  for (int s = 0; s < 2; ++s) {
    const int ti = (s == 0) ? (p == 0 ? 0 : 1) : (p == 0 ? 3 : 2);
    const int i0 = ti * 128;
    const int i = i0 + row;
    const int ntiles = 2 * ti + 2;

    // A fragments: wave w covers rows i0 + w*16 + col16; k = c*32 + quad*8
    f16x8 ah[2], al[2];
#pragma unroll
    for (int c = 0; c < 2; ++c) {
      const float* ptr =
          Qb + (long)(i0 + wave * 16 + col16) * 64 + c * 32 + quad * 8;
      float4 x0 = *(const float4*)ptr, x1 = *(const float4*)(ptr + 4);
      float xs[8] = {x0.x, x0.y, x0.z, x0.w, x1.x, x1.y, x1.z, x1.w};
      f16x8 hv, lv;
#pragma unroll
      for (int e = 0; e < 8; ++e) {
        F16Pair pr = splitf(xs[e]);
        hv[e] = pr.hi; lv[e] = pr.lo;
      }
      ah[c] = hv; al[c] = lv;
    }

    float topv[8];
    int topi[8];
#pragma unroll
    for (int t = 0; t < 8; ++t) { topv[t] = -1e30f; topi[t] = 0; }
    float kth = -1e30f;

    // preload tile-0 B-frags (16 x f16x8 = 64 VGPRs)
    f16x8 pb[16];
#pragma unroll
    for (int ni = 0; ni < 4; ++ni)
#pragma unroll
      for (int c = 0; c < 2; ++c) {
        const _Float16* ptr = Kb + (long)(ni * 16 + col16) * 128 + c * 32 + quad * 8;
        pb[ni * 4 + c * 2 + 0] = *(const f16x8*)ptr;
        pb[ni * 4 + c * 2 + 1] = *(const f16x8*)(ptr + 64);
      }

    for (int t = 0; t < ntiles; ++t) {
      __syncthreads();  // prior scan / prior i-tile merge done with shbuf

      // ---- strip compute from prefetched frags ----
#pragma unroll
      for (int ni = 0; ni < 4; ++ni) {
        f32x4 a = (f32x4){0.f, 0.f, 0.f, 0.f};
#pragma unroll
        for (int c = 0; c < 2; ++c) {
          const f16x8 bhf = pb[ni * 4 + c * 2], blf = pb[ni * 4 + c * 2 + 1];
          a = __builtin_amdgcn_mfma_f32_16x16x32_f16(al[c], blf, a, 0, 0, 0);
          a = __builtin_amdgcn_mfma_f32_16x16x32_f16(ah[c], blf, a, 0, 0, 0);
          a = __builtin_amdgcn_mfma_f32_16x16x32_f16(al[c], bhf, a, 0, 0, 0);
          a = __builtin_amdgcn_mfma_f32_16x16x32_f16(ah[c], bhf, a, 0, 0, 0);
        }
        const int row_l = wave * 16 + quad * 4;
        const int col_l = ni * 16 + col16;
#pragma unroll
        for (int r = 0; r < 4; ++r) Ss[row_l + r][col_l] = a[r];
      }

      // ---- prefetch next tile's B-frags (in flight during scan+barrier) ----
      if (t + 1 < ntiles) {
        const _Float16* Kt = Kb + (long)(t + 1) * 64 * 128;
#pragma unroll
        for (int ni = 0; ni < 4; ++ni)
#pragma unroll
          for (int c = 0; c < 2; ++c) {
            const _Float16* ptr =
                Kt + (long)(ni * 16 + col16) * 128 + c * 32 + quad * 8;
            pb[ni * 4 + c * 2 + 0] = *(const f16x8*)ptr;
            pb[ni * 4 + c * 2 + 1] = *(const f16x8*)(ptr + 64);
          }
      }
      __syncthreads();

      // ---- scan: two 8-col batches, compile-time unrolled, causal-masked --
      const int cbase = t * 64 + part * 16;
#pragma unroll
      for (int half = 0; half < 2; ++half) {
        float sv[8];
#pragma unroll
        for (int cc = 0; cc < 8; ++cc)
          sv[cc] = Ss[row][part * 16 + half * 8 + cc];
#pragma unroll
        for (int cc = 0; cc < 8; ++cc) {
          const float sc = sv[cc];
          const int ci0 = cbase + half * 8 + cc;
          if (ci0 < i && sc > kth) {
            float cv = sc;
            int ci = ci0;
#pragma unroll
            for (int u = 0; u < 8; ++u) {
              if (cv > topv[u]) {
                float tv = topv[u]; topv[u] = cv; cv = tv;
                int tix = topi[u]; topi[u] = ci; ci = tix;
              }
            }
#pragma unroll
            for (int u = 0; u < 8; ++u)
              if (u == kidx - 1) kth = topv[u];
          }
        }
      }
    }

    // ---- deposit candidates (Ss no longer needed) ----
    __syncthreads();
#pragma unroll
    for (int u = 0; u < 8; ++u) {
      candv[row][part * 8 + u] = topv[u];
      candi[row][part * 8 + u] = topi[u];
    }
    __syncthreads();

    // ---- per-row merge of 32 candidates -> exact top-8, weights, write ----
    if (tid < 128) {
      float mv[8];
      int mi_[8];
#pragma unroll
      for (int u = 0; u < 8; ++u) { mv[u] = -1e30f; mi_[u] = 0; }
#pragma unroll
      for (int j = 0; j < 32; ++j) {
        float cv = candv[tid][j];
        int ci = candi[tid][j];
        if (cv > mv[7]) {
#pragma unroll
          for (int u = 0; u < 8; ++u) {
            if (cv > mv[u]) {
              float tv = mv[u]; mv[u] = cv; cv = tv;
              int tix = mi_[u]; mi_[u] = ci; ci = tix;
            }
          }
        }
      }

      const float m = mv[0];
      float w[8];
      float num = 0.f;
#pragma unroll
      for (int u = 0; u < 8; ++u) {
        const bool valid = (u < kidx) && (mv[u] > -1e29f);
        w[u] = valid ? expf((mv[u] - m) * 0.125f) : 0.f;
        num += w[u];
      }
      const float inv = (num > 0.f) ? 1.f / num : 0.f;  // row 0: zero weights

      float* Qrow = qh + ((long)bh * 512 + i0 + tid) * 64;
#pragma unroll
      for (int u = 0; u < 8; ++u) Qrow[u] = w[u] * inv;
      int* ip = (int*)Qrow;
#pragma unroll
      for (int u = 0; u < 8; ++u) ip[8 + u] = mi_[u];
    }
    // next i-tile's first loop-top __syncthreads() protects shbuf reuse
  }
}

// ---------------------------------------------------------------------------
// gather: out_attn[row] = sum_t w_t * vh[idx_t]   (bf16 concat layout)
// ---------------------------------------------------------------------------
__global__ __launch_bounds__(256) void gather_kernel(
    const float* __restrict__ qh_sel, const unsigned short* __restrict__ vh,
    unsigned short* __restrict__ attn) {
  const int row = blockIdx.x * 256 + (int)threadIdx.x;  // [0, 131072)
  const int bh = row >> 9, i = row & 511;
  const int b = bh >> 3, h = bh & 7;

  const float* sel = qh_sel + (long)row * 64;
  const int* ip = (const int*)sel;

  float o[64];
#pragma unroll
  for (int d = 0; d < 64; ++d) o[d] = 0.f;

#pragma unroll
  for (int t = 0; t < 8; ++t) {
    const float w = sel[t];
    if (w != 0.f) {
      const unsigned short* Vrow = vh + ((long)bh * 512 + ip[8 + t]) * 64;
#pragma unroll
      for (int c = 0; c < 8; ++c) {
        uint4 raw = *(const uint4*)(Vrow + c * 8);
        float f[8];
        unpack8(raw, f);
#pragma unroll
        for (int d = 0; d < 8; ++d) o[c * 8 + d] = fmaf(w, f[d], o[c * 8 + d]);
      }
    }
  }

  const long ob = ((long)(b * 512 + i)) * 512 + h * 64;
#pragma unroll
  for (int c = 0; c < 8; ++c) {
    uint4 wv;
    wv.x = (unsigned)f2bf(o[c * 8 + 0]) | ((unsigned)f2bf(o[c * 8 + 1]) << 16);
    wv.y = (unsigned)f2bf(o[c * 8 + 2]) | ((unsigned)f2bf(o[c * 8 + 3]) << 16);
    wv.z = (unsigned)f2bf(o[c * 8 + 4]) | ((unsigned)f2bf(o[c * 8 + 5]) << 16);
    wv.w = (unsigned)f2bf(o[c * 8 + 6]) | ((unsigned)f2bf(o[c * 8 + 7]) << 16);
    *(uint4*)&attn[ob + c * 8] = wv;
  }
}

// ---------------------------------------------------------------------------
extern "C" void kernel_launch(void* const* d_in, const int* in_sizes, int n_in,
                              void* d_out, int out_size, void* d_ws, size_t ws_size,
                              hipStream_t stream) {
  const float* q   = (const float*)d_in[0];
  const float* k   = (const float*)d_in[1];
  const float* v   = (const float*)d_in[2];
  const float* w_q = (const float*)d_in[3];
  const float* b_q = (const float*)d_in[4];
  const float* w_k = (const float*)d_in[5];
  const float* b_k = (const float*)d_in[6];
  const float* w_v = (const float*)d_in[7];
  const float* b_v = (const float*)d_in[8];
  const float* w_o = (const float*)d_in[9];
  const float* b_o = (const float*)d_in[10];
  const int* kidx  = (const int*)d_in[11];

  // workspace (64 MiB): qh fp32 32M (also holds sel output) | khl f16-hilo
  // 32M. After attn_sel consumes khl, that region is reused for vh bf16
  // (16M) + attn bf16 (16M). Stream order makes the overlay safe.
  const long NE = (long)Bn * Hn * Sn * DKn;  // 8388608
  float* qh = (float*)d_ws;
  _Float16* khl = (_Float16*)(qh + NE);      // 131072 rows x 128 f16
  unsigned short* vh   = (unsigned short*)khl;
  unsigned short* attn = vh + NE;

  const dim3 gg(128, 4), bb(256);
  gemm_qk_kernel<<<dim3(128, 4, 2), bb, 0, stream>>>(q, w_q, b_q, qh,
                                                     k, w_k, b_k, khl);
  attn_sel_kernel<<<dim3(2, 256), dim3(512), 0, stream>>>(qh, khl, kidx);
  gemm_kernel<false, true><<<gg, bb, 0, stream>>>(v, w_v, b_v, vh);
  gather_kernel<<<512, bb, 0, stream>>>(qh, vh, attn);
  gemm_kernel<true, false><<<gg, bb, 0, stream>>>(attn, w_o, b_o, (float*)d_out);
}